// Round 17
// baseline (30.531 us; speedup 1.0000x reference)
//
#include <hip/hip_runtime.h>
#include <hip/hip_fp16.h>

#define EPSF 1e-20f

constexpr int Hh = 768, Ww = 768, Bb = 4;
constexpr int PLANE = Hh * Ww;
constexpr int TSX = 32, TSY = 24;             // output tile (w x h)
constexpr int R3Y = TSY + 6, R3X = TSX + 6;   // 30 x 38 halo-3 (dq, c)
constexpr int R2Y = TSY + 4, R2X = TSX + 4;   // 28 x 36 halo-2 (tc, ts)
constexpr int R1Y = TSY + 2, R1X = TSX + 2;   // 26 x 34 halo-1 (s)

struct Smem {
    float2 s_qc[R3Y][R3X];   // (.x = dq = d/(c+eps), .y = c)
    float2 s_t[R2Y][R2X];    // (tc, ts)
    __half s_s[R1Y][R1X];    // s (half), 0 outside image
    float  sw[20];           // wd[0..8], ws[9..17], wps, wpow
    float  swraw[18];        // unnormalized softplus values
};

// r16 structure minus the C2 staging phase: Phase C stores scs_out/cs_out
// directly (lane-shifted but segment-aligned); Phase D writes only x_out.
template<bool EDGE>
__device__ __forceinline__
void tile_body(Smem& sm, int b, int ty0, int tx0,
               const float* __restrict__ x, const float* __restrict__ scs,
               const float* __restrict__ cs,
               const float* __restrict__ w_sp_d, const float* __restrict__ w_sp_s,
               const float* __restrict__ w_pow_s, const float* __restrict__ w_prop_s,
               float* __restrict__ out) {
    auto& s_qc = sm.s_qc; auto& s_t = sm.s_t; auto& s_s = sm.s_s;
    auto& sw = sm.sw; auto& swraw = sm.swraw;

    const int tid = threadIdx.x;
    const float* dcd = x + b * PLANE;
    const float* cd  = x + (Bb + b) * PLANE;

    // ---- parallel weight prep (lanes 0..10 of wave 0; wave-lockstep safe) ----
    if (tid < 9) {
        int r = tid / 3, c = tid - r * 3;
        int cc = (c == 2) ? 0 : c;              // mirrored 3rd column
        swraw[tid]     = log1pf(expf(w_sp_d[r * 2 + cc]));
        swraw[9 + tid] = log1pf(expf(w_sp_s[r * 2 + cc]));
    }
    if (tid == 9)  sw[18] = 1.f / (1.f + expf(-w_prop_s[0]));   // wps
    if (tid == 10) sw[19] = log1pf(expf(w_pow_s[0]));           // wpow
    if (tid < 9) {   // same-wave: raw writes complete (lockstep) before reads
        float sum_d = 0.f, sum_s = 0.f;
        #pragma unroll
        for (int k = 0; k < 9; ++k) { sum_d += swraw[k]; sum_s += swraw[9 + k]; }
        sw[tid]     = swraw[tid]     / sum_d;
        sw[9 + tid] = swraw[9 + tid] / sum_s;
    }

    // ---- Phase A: vectorized load at halo-3 (30 rows x 10 float4 segs) ----
    for (int it = tid; it < R3Y * 10; it += 256) {   // 300 items
        int row = it / 10, seg = it - row * 10;
        int gy = ty0 - 3 + row;
        int gxb = tx0 - 4 + seg * 4;
        float4 vd4, vc4;
        if constexpr (!EDGE) {
            vd4 = *(const float4*)(dcd + gy * Ww + gxb);
            vc4 = *(const float4*)(cd  + gy * Ww + gxb);
        } else {
            vd4 = make_float4(0.f, 0.f, 0.f, 0.f);
            vc4 = vd4;
            if ((unsigned)gy < (unsigned)Hh) {
                bool safe = (seg > 0 && seg < 9) || (seg == 0 ? (tx0 > 0) : (tx0 + TSX < Ww));
                if (safe) {
                    vd4 = *(const float4*)(dcd + gy * Ww + gxb);
                    vc4 = *(const float4*)(cd  + gy * Ww + gxb);
                } else {
                    if ((unsigned)(gxb + 0) < (unsigned)Ww) { vd4.x = dcd[gy*Ww+gxb+0]; vc4.x = cd[gy*Ww+gxb+0]; }
                    if ((unsigned)(gxb + 1) < (unsigned)Ww) { vd4.y = dcd[gy*Ww+gxb+1]; vc4.y = cd[gy*Ww+gxb+1]; }
                    if ((unsigned)(gxb + 2) < (unsigned)Ww) { vd4.z = dcd[gy*Ww+gxb+2]; vc4.z = cd[gy*Ww+gxb+2]; }
                    if ((unsigned)(gxb + 3) < (unsigned)Ww) { vd4.w = dcd[gy*Ww+gxb+3]; vc4.w = cd[gy*Ww+gxb+3]; }
                }
            }
        }
        int lxb = seg * 4 - 1;   // lx of component 0
        if ((unsigned)(lxb + 0) < (unsigned)R3X) s_qc[row][lxb + 0] = make_float2(vd4.x / (vc4.x + EPSF), vc4.x);
        if ((unsigned)(lxb + 1) < (unsigned)R3X) s_qc[row][lxb + 1] = make_float2(vd4.y / (vc4.y + EPSF), vc4.y);
        if ((unsigned)(lxb + 2) < (unsigned)R3X) s_qc[row][lxb + 2] = make_float2(vd4.z / (vc4.z + EPSF), vc4.z);
        if ((unsigned)(lxb + 3) < (unsigned)R3X) s_qc[row][lxb + 3] = make_float2(vd4.w / (vc4.w + EPSF), vc4.w);
    }

    // ---- Prefetch cs/scs for Phase B (36 cols x 7 groups of 4 rows) ----
    const int xB = tid % R2X;          // 0..35
    const int tyB = tid / R2X;         // active < 7 (252 threads)
    const int yb0 = tyB * 4;
    float pcs[4], pscs[4];
    if (tyB < 7) {
        int gx = tx0 - 2 + xB;
        if constexpr (!EDGE) {
            #pragma unroll
            for (int j = 0; j < 4; ++j) {
                int idx = b * PLANE + (ty0 - 2 + yb0 + j) * Ww + gx;
                pcs[j]  = cs[idx];
                pscs[j] = scs[idx];
            }
        } else {
            bool colok = (unsigned)gx < (unsigned)Ww;
            #pragma unroll
            for (int j = 0; j < 4; ++j) {
                int gy = ty0 - 2 + yb0 + j;
                bool ok = colok && (unsigned)gy < (unsigned)Hh;
                int idx = ok ? (b * PLANE + gy * Ww + gx) : 0;
                pcs[j]  = ok ? cs[idx]  : 0.f;
                pscs[j] = ok ? scs[idx] : 0.f;
            }
        }
    }
    __syncthreads();

    const float wps  = sw[18];
    const float wpow = sw[19];
    const float onemw = 1.f - wps;

    // ---- Phase B: stage 1, column sweep. Hierarchical first-wins argmax:
    // row-max over dx (k-minor) then combine over dy (k-major) — exactly
    // reproduces jnp.argmax first-occurrence order.
    if (tyB < 7) {
        float ma[3], md[3], mc[3];    // jmax row-partials (key, dq, c)
        float nv[3], nq[3];           // jmin row-partials (vc, dq+eps)
#define HROW_B(rr, slot) { \
        float2 q0 = s_qc[rr][xB]; float2 q1 = s_qc[rr][xB + 1]; float2 q2 = s_qc[rr][xB + 2]; \
        float a0 = q0.x * q0.y, a1 = q1.x * q1.y, a2 = q2.x * q2.y; \
        float A = a0, D = q0.x, C = q0.y; \
        if (a1 > A) { A = a1; D = q1.x; C = q1.y; } \
        if (a2 > A) { A = a2; D = q2.x; C = q2.y; } \
        ma[slot] = A; md[slot] = D; mc[slot] = C; \
        float V = q0.y, Q = q0.x + EPSF; \
        float e1 = q1.x + EPSF, e2 = q2.x + EPSF; \
        if (q1.y * Q > V * e1) { V = q1.y; Q = e1; } \
        if (q2.y * Q > V * e2) { V = q2.y; Q = e2; } \
        nv[slot] = V; nq[slot] = Q; }
        HROW_B(yb0 + 0, 0)
        HROW_B(yb0 + 1, 1)
        #pragma unroll
        for (int j = 0; j < 4; ++j) {
            const int sl2 = (j + 2) % 3, s0 = j % 3, s1 = (j + 1) % 3;
            HROW_B(yb0 + j + 2, sl2)
            float A = ma[s0], D = md[s0], C = mc[s0];
            if (ma[s1]  > A) { A = ma[s1];  D = md[s1];  C = mc[s1];  }
            if (ma[sl2] > A) { A = ma[sl2]; D = md[sl2]; C = mc[sl2]; }
            float V = nv[s0], Q = nq[s0];
            if (nv[s1]  * Q > V * nq[s1])  { V = nv[s1];  Q = nq[s1];  }
            if (nv[sl2] * Q > V * nq[sl2]) { V = nv[sl2]; Q = nq[sl2]; }
            const int yb = yb0 + j;
            bool in_img;
            if constexpr (!EDGE) in_img = true;
            else {
                const int gy = ty0 - 2 + yb, gx = tx0 - 2 + xB;
                in_img = (unsigned)gy < (unsigned)Hh && (unsigned)gx < (unsigned)Ww;
            }
            float tc = 0.f, ts = 0.f;
            if (in_img) {
                float s_new = __builtin_amdgcn_exp2f(wpow *
                    (__builtin_amdgcn_logf(Q) - __builtin_amdgcn_logf(D + EPSF)));
                float cs_new = C * V;
                tc = pcs[j]  * wps + cs_new * onemw;
                ts = pscs[j] * wps + s_new * cs_new * onemw;
            }
            s_t[yb][xB] = make_float2(tc, ts);
        }
    }
    __syncthreads();

    // ---- Phase C: stage 2 conv, column sweep (34 cols x 7 groups of 4) ----
    // Interior pixels store scs_out/cs_out DIRECTLY (lane-shifted by 1 but
    // within the same aligned 128B segments); s into LDS for stage 3.
    const int xC = tid % R1X;          // 0..33
    const int tyC = tid / R1X;         // active < 7 (238 threads)
    const int yc0 = tyC * 4;
    if (tyC < 7) {
        const float wa0 = sw[9],  wb0 = sw[10];
        const float wa1 = sw[12], wb1 = sw[13];
        const float wa2 = sw[15], wb2 = sw[16];
        float2 u[3], tm[3];
#define HROW_C(rr, slot) { \
        float2 t0 = s_t[rr][xC]; float2 t1 = s_t[rr][xC + 1]; float2 t2 = s_t[rr][xC + 2]; \
        u[slot] = make_float2(t0.x + t2.x, t0.y + t2.y); tm[slot] = t1; }
        HROW_C(yc0 + 0, 0)
        HROW_C(yc0 + 1, 1)
        #pragma unroll
        for (int j = 0; j < 4; ++j) {
            const int yc = yc0 + j;
            if (yc < R1Y) {
                const int sl2 = (j + 2) % 3, s0 = j % 3, s1 = (j + 1) % 3;
                HROW_C(yc + 2, sl2)
                float accC = wa0 * u[s0].x + wb0 * tm[s0].x
                           + wa1 * u[s1].x + wb1 * tm[s1].x
                           + wa2 * u[sl2].x + wb2 * tm[sl2].x;
                float accS = wa0 * u[s0].y + wb0 * tm[s0].y
                           + wa1 * u[s1].y + wb1 * tm[s1].y
                           + wa2 * u[sl2].y + wb2 * tm[sl2].y;
                bool in_img;
                if constexpr (!EDGE) in_img = true;
                else {
                    const int gy = ty0 - 1 + yc, gx = tx0 - 1 + xC;
                    in_img = (unsigned)gy < (unsigned)Hh && (unsigned)gx < (unsigned)Ww;
                }
                s_s[yc][xC] = __float2half(
                    in_img ? (accS * __builtin_amdgcn_rcpf(accC + EPSF)) : 0.f);
                // tile-interior pixels are the tile's outputs (always in-image)
                const int iy = yc - 1, ix = xC - 1;
                if ((unsigned)iy < (unsigned)TSY && (unsigned)ix < (unsigned)TSX) {
                    int idx = (ty0 + iy) * Ww + (tx0 + ix);
                    out[(8 + b)  * PLANE + idx] = accS;
                    out[(12 + b) * PLANE + idx] = accC;
                }
            }
        }
    }
    __syncthreads();   // s_s ready

    // ---- Phase D: stage 3 + x_out writes (32 cols x 8 groups of 3 rows) ----
    // sc factored out of the 8 non-center taps (verified bit-safe r14-r16).
    {
        const int xD = tid & 31, tyD = tid >> 5;
        const int yd0 = tyD * 3;
        float wdk[9];
        #pragma unroll
        for (int k = 0; k < 9; ++k) wdk[k] = sw[k];
        float  srw[3][3];
        float2 qrw[3][3];
#define HROW_D(rr, slot) { \
        srw[slot][0] = __half2float(s_s[rr][xD]); \
        srw[slot][1] = __half2float(s_s[rr][xD + 1]); \
        srw[slot][2] = __half2float(s_s[rr][xD + 2]); \
        qrw[slot][0] = s_qc[rr + 2][xD + 2]; qrw[slot][1] = s_qc[rr + 2][xD + 3]; qrw[slot][2] = s_qc[rr + 2][xD + 4]; }
        HROW_D(yd0 + 0, 0)
        HROW_D(yd0 + 1, 1)
#define TAP_F(slot, kk, cc2) { \
        float t = wdk[kk] * srw[slot][cc2]; \
        float2 q = qrw[slot][cc2]; \
        dn_p += t; \
        nd_p = fmaf(t, q.x * (q.y + EPSF), nd_p); \
        nc_p = fmaf(t, q.y, nc_p); }
        #pragma unroll
        for (int j = 0; j < 3; ++j) {
            const int sl2 = (j + 2) % 3, s0 = j % 3, s1 = (j + 1) % 3;
            HROW_D(yd0 + j + 2, sl2)
            float sc = srw[s1][1];
            float nd_p = 0.f, nc_p = 0.f, dn_p = 0.f;
            TAP_F(s0, 0, 0) TAP_F(s0, 1, 1) TAP_F(s0, 2, 2)
            TAP_F(s1, 3, 0)                 TAP_F(s1, 5, 2)
            TAP_F(sl2, 6, 0) TAP_F(sl2, 7, 1) TAP_F(sl2, 8, 2)
            const float w4 = wdk[4];
            float2 q4 = qrw[s1][1];
            float d4 = q4.x * (q4.y + EPSF);
            float den = fmaf(sc, dn_p, w4) + EPSF;
            float nd  = fmaf(sc, nd_p, w4 * d4);
            float nc  = fmaf(sc, nc_p, w4 * q4.y);
            float rinv = __builtin_amdgcn_rcpf(den);
            const int iy = yd0 + j;
            int idx = (ty0 + iy) * Ww + (tx0 + xD);
            out[(2 * b)     * PLANE + idx] = nd * rinv;   // x_out d-part
            out[(2 * b + 1) * PLANE + idx] = nc * rinv;   // x_out c-part
        }
    }
}

// Single launch: blocks 0..2639 interior (no checks), 2640..3071 edge ring.
__global__ __launch_bounds__(256)
void fused_all(const float* __restrict__ x, const float* __restrict__ scs,
               const float* __restrict__ cs,
               const float* __restrict__ w_sp_d, const float* __restrict__ w_sp_s,
               const float* __restrict__ w_pow_s, const float* __restrict__ w_prop_s,
               float* __restrict__ out) {
    __shared__ Smem sm;
    const int orig = blockIdx.x;
    if (orig < 2640) {
        // 2640 = 8 XCDs x 330; interior tiles ty 1..30, tx 1..22
        const int swz = (orig & 7) * 330 + (orig >> 3);
        const int b   = swz / 660;
        const int rem = swz - b * 660;
        const int ty0 = (1 + rem / 22) * TSY;
        const int tx0 = (1 + rem % 22) * TSX;
        tile_body<false>(sm, b, ty0, tx0, x, scs, cs, w_sp_d, w_sp_s,
                         w_pow_s, w_prop_s, out);
    } else {
        // 432 = 8 XCDs x 54; ring tiles of the 24(x) x 32(y) tile grid
        const int o2  = orig - 2640;
        const int swz = (o2 & 7) * 54 + (o2 >> 3);
        const int b   = swz / 108;
        const int rem = swz - b * 108;
        int tyT, txT;
        if (rem < 24)      { tyT = 0;  txT = rem; }
        else if (rem < 48) { tyT = 31; txT = rem - 24; }
        else if (rem < 78) { txT = 0;  tyT = 1 + (rem - 48); }
        else               { txT = 23; tyT = 1 + (rem - 78); }
        tile_body<true>(sm, b, tyT * TSY, txT * TSX, x, scs, cs, w_sp_d, w_sp_s,
                        w_pow_s, w_prop_s, out);
    }
}

extern "C" void kernel_launch(void* const* d_in, const int* in_sizes, int n_in,
                              void* d_out, int out_size, void* d_ws, size_t ws_size,
                              hipStream_t stream) {
    const float* x        = (const float*)d_in[0];
    const float* scs      = (const float*)d_in[1];
    const float* cs       = (const float*)d_in[2];
    // d_in[3] = w_channel_d (1,1) -> normalizes to 1, unused
    const float* w_sp_d   = (const float*)d_in[4];
    const float* w_pow_s  = (const float*)d_in[5];
    const float* w_prop_s = (const float*)d_in[6];
    // d_in[7] = w_channel_s (1,1) -> normalizes to 1, unused
    const float* w_sp_s   = (const float*)d_in[8];
    float* out  = (float*)d_out;

    fused_all<<<dim3(3072), 256, 0, stream>>>(x, scs, cs, w_sp_d, w_sp_s,
                                              w_pow_s, w_prop_s, out);
}

// Round 18
// 29.413 us; speedup vs baseline: 1.0380x; 1.0380x over previous
//
#include <hip/hip_runtime.h>
#include <hip/hip_fp16.h>

#define EPSF 1e-20f

constexpr int Hh = 768, Ww = 768, Bb = 4;
constexpr int PLANE = Hh * Ww;
constexpr int TSX = 32, TSY = 24;             // output tile (w x h)
constexpr int R3Y = TSY + 6, R3X = TSX + 6;   // 30 x 38 halo-3 (dq, c)
constexpr int R2Y = TSY + 4, R2X = TSX + 4;   // 28 x 36 halo-2 (tc, ts)
constexpr int R1Y = TSY + 2, R1X = TSX + 2;   // 26 x 34 halo-1 (s)

struct Smem {
    float2 s_qc[R3Y][R3X];   // (.x = dq = d/(c+eps), .y = c)
    float2 s_t[R2Y][R2X];    // B: (tc,ts); C2+: (accC,accS)
    __half s_s[R1Y][R1X];    // s (half), 0 outside image
    float  sw[20];           // wd[0..8], ws[9..17], wps, wpow
    float  swraw[18];        // unnormalized softplus values
};

// r16 tile body verbatim (weight prep hoisted to caller).
// EDGE=false folds every bounds check away (interior tiles).
template<bool EDGE>
__device__ __forceinline__
void tile_body(Smem& sm, int b, int ty0, int tx0,
               const float* __restrict__ x, const float* __restrict__ scs,
               const float* __restrict__ cs, float* __restrict__ out) {
    auto& s_qc = sm.s_qc; auto& s_t = sm.s_t; auto& s_s = sm.s_s;
    auto& sw = sm.sw;

    const int tid = threadIdx.x;
    const float* dcd = x + b * PLANE;
    const float* cd  = x + (Bb + b) * PLANE;

    // ---- Phase A: vectorized load at halo-3 (30 rows x 10 float4 segs) ----
    for (int it = tid; it < R3Y * 10; it += 256) {   // 300 items
        int row = it / 10, seg = it - row * 10;
        int gy = ty0 - 3 + row;
        int gxb = tx0 - 4 + seg * 4;
        float4 vd4, vc4;
        if constexpr (!EDGE) {
            vd4 = *(const float4*)(dcd + gy * Ww + gxb);
            vc4 = *(const float4*)(cd  + gy * Ww + gxb);
        } else {
            vd4 = make_float4(0.f, 0.f, 0.f, 0.f);
            vc4 = vd4;
            if ((unsigned)gy < (unsigned)Hh) {
                bool safe = (seg > 0 && seg < 9) || (seg == 0 ? (tx0 > 0) : (tx0 + TSX < Ww));
                if (safe) {
                    vd4 = *(const float4*)(dcd + gy * Ww + gxb);
                    vc4 = *(const float4*)(cd  + gy * Ww + gxb);
                } else {
                    if ((unsigned)(gxb + 0) < (unsigned)Ww) { vd4.x = dcd[gy*Ww+gxb+0]; vc4.x = cd[gy*Ww+gxb+0]; }
                    if ((unsigned)(gxb + 1) < (unsigned)Ww) { vd4.y = dcd[gy*Ww+gxb+1]; vc4.y = cd[gy*Ww+gxb+1]; }
                    if ((unsigned)(gxb + 2) < (unsigned)Ww) { vd4.z = dcd[gy*Ww+gxb+2]; vc4.z = cd[gy*Ww+gxb+2]; }
                    if ((unsigned)(gxb + 3) < (unsigned)Ww) { vd4.w = dcd[gy*Ww+gxb+3]; vc4.w = cd[gy*Ww+gxb+3]; }
                }
            }
        }
        int lxb = seg * 4 - 1;   // lx of component 0
        if ((unsigned)(lxb + 0) < (unsigned)R3X) s_qc[row][lxb + 0] = make_float2(vd4.x / (vc4.x + EPSF), vc4.x);
        if ((unsigned)(lxb + 1) < (unsigned)R3X) s_qc[row][lxb + 1] = make_float2(vd4.y / (vc4.y + EPSF), vc4.y);
        if ((unsigned)(lxb + 2) < (unsigned)R3X) s_qc[row][lxb + 2] = make_float2(vd4.z / (vc4.z + EPSF), vc4.z);
        if ((unsigned)(lxb + 3) < (unsigned)R3X) s_qc[row][lxb + 3] = make_float2(vd4.w / (vc4.w + EPSF), vc4.w);
    }

    // ---- Prefetch cs/scs for Phase B (36 cols x 7 groups of 4 rows) ----
    const int xB = tid % R2X;          // 0..35
    const int tyB = tid / R2X;         // active < 7 (252 threads)
    const int yb0 = tyB * 4;
    float pcs[4], pscs[4];
    if (tyB < 7) {
        int gx = tx0 - 2 + xB;
        if constexpr (!EDGE) {
            #pragma unroll
            for (int j = 0; j < 4; ++j) {
                int idx = b * PLANE + (ty0 - 2 + yb0 + j) * Ww + gx;
                pcs[j]  = cs[idx];
                pscs[j] = scs[idx];
            }
        } else {
            bool colok = (unsigned)gx < (unsigned)Ww;
            #pragma unroll
            for (int j = 0; j < 4; ++j) {
                int gy = ty0 - 2 + yb0 + j;
                bool ok = colok && (unsigned)gy < (unsigned)Hh;
                int idx = ok ? (b * PLANE + gy * Ww + gx) : 0;
                pcs[j]  = ok ? cs[idx]  : 0.f;
                pscs[j] = ok ? scs[idx] : 0.f;
            }
        }
    }
    __syncthreads();

    const float wps  = sw[18];
    const float wpow = sw[19];
    const float onemw = 1.f - wps;

    // ---- Phase B: stage 1, column sweep. Hierarchical first-wins argmax:
    // row-max over dx (k-minor) then combine over dy (k-major) — exactly
    // reproduces jnp.argmax first-occurrence order.
    if (tyB < 7) {
        float ma[3], md[3], mc[3];    // jmax row-partials (key, dq, c)
        float nv[3], nq[3];           // jmin row-partials (vc, dq+eps)
#define HROW_B(rr, slot) { \
        float2 q0 = s_qc[rr][xB]; float2 q1 = s_qc[rr][xB + 1]; float2 q2 = s_qc[rr][xB + 2]; \
        float a0 = q0.x * q0.y, a1 = q1.x * q1.y, a2 = q2.x * q2.y; \
        float A = a0, D = q0.x, C = q0.y; \
        if (a1 > A) { A = a1; D = q1.x; C = q1.y; } \
        if (a2 > A) { A = a2; D = q2.x; C = q2.y; } \
        ma[slot] = A; md[slot] = D; mc[slot] = C; \
        float V = q0.y, Q = q0.x + EPSF; \
        float e1 = q1.x + EPSF, e2 = q2.x + EPSF; \
        if (q1.y * Q > V * e1) { V = q1.y; Q = e1; } \
        if (q2.y * Q > V * e2) { V = q2.y; Q = e2; } \
        nv[slot] = V; nq[slot] = Q; }
        HROW_B(yb0 + 0, 0)
        HROW_B(yb0 + 1, 1)
        #pragma unroll
        for (int j = 0; j < 4; ++j) {
            const int sl2 = (j + 2) % 3, s0 = j % 3, s1 = (j + 1) % 3;
            HROW_B(yb0 + j + 2, sl2)
            float A = ma[s0], D = md[s0], C = mc[s0];
            if (ma[s1]  > A) { A = ma[s1];  D = md[s1];  C = mc[s1];  }
            if (ma[sl2] > A) { A = ma[sl2]; D = md[sl2]; C = mc[sl2]; }
            float V = nv[s0], Q = nq[s0];
            if (nv[s1]  * Q > V * nq[s1])  { V = nv[s1];  Q = nq[s1];  }
            if (nv[sl2] * Q > V * nq[sl2]) { V = nv[sl2]; Q = nq[sl2]; }
            const int yb = yb0 + j;
            bool in_img;
            if constexpr (!EDGE) in_img = true;
            else {
                const int gy = ty0 - 2 + yb, gx = tx0 - 2 + xB;
                in_img = (unsigned)gy < (unsigned)Hh && (unsigned)gx < (unsigned)Ww;
            }
            float tc = 0.f, ts = 0.f;
            if (in_img) {
                float s_new = __builtin_amdgcn_exp2f(wpow *
                    (__builtin_amdgcn_logf(Q) - __builtin_amdgcn_logf(D + EPSF)));
                float cs_new = C * V;
                tc = pcs[j]  * wps + cs_new * onemw;
                ts = pscs[j] * wps + s_new * cs_new * onemw;
            }
            s_t[yb][xB] = make_float2(tc, ts);
        }
    }
    __syncthreads();

    // ---- Phase C: stage 2 conv, column sweep (34 cols x 7 groups of 4) ----
    const int xC = tid % R1X;          // 0..33
    const int tyC = tid / R1X;         // active < 7 (238 threads)
    const int yc0 = tyC * 4;
    float2 cres[4];
    if (tyC < 7) {
        const float wa0 = sw[9],  wb0 = sw[10];
        const float wa1 = sw[12], wb1 = sw[13];
        const float wa2 = sw[15], wb2 = sw[16];
        float2 u[3], tm[3];
#define HROW_C(rr, slot) { \
        float2 t0 = s_t[rr][xC]; float2 t1 = s_t[rr][xC + 1]; float2 t2 = s_t[rr][xC + 2]; \
        u[slot] = make_float2(t0.x + t2.x, t0.y + t2.y); tm[slot] = t1; }
        HROW_C(yc0 + 0, 0)
        HROW_C(yc0 + 1, 1)
        #pragma unroll
        for (int j = 0; j < 4; ++j) {
            const int yc = yc0 + j;
            if (yc < R1Y) {
                const int sl2 = (j + 2) % 3, s0 = j % 3, s1 = (j + 1) % 3;
                HROW_C(yc + 2, sl2)
                float accC = wa0 * u[s0].x + wb0 * tm[s0].x
                           + wa1 * u[s1].x + wb1 * tm[s1].x
                           + wa2 * u[sl2].x + wb2 * tm[sl2].x;
                float accS = wa0 * u[s0].y + wb0 * tm[s0].y
                           + wa1 * u[s1].y + wb1 * tm[s1].y
                           + wa2 * u[sl2].y + wb2 * tm[sl2].y;
                bool in_img;
                if constexpr (!EDGE) in_img = true;
                else {
                    const int gy = ty0 - 1 + yc, gx = tx0 - 1 + xC;
                    in_img = (unsigned)gy < (unsigned)Hh && (unsigned)gx < (unsigned)Ww;
                }
                s_s[yc][xC] = __float2half(
                    in_img ? (accS * __builtin_amdgcn_rcpf(accC + EPSF)) : 0.f);
                cres[j] = make_float2(accC, accS);
            }
        }
    }
    __syncthreads();   // all s_t reads done; s_s ready

    // ---- Phase C2: dump conv results into dead s_t for aligned writes ----
    if (tyC < 7) {
        #pragma unroll
        for (int j = 0; j < 4; ++j) {
            const int yc = yc0 + j;
            if (yc < R1Y) s_t[yc][xC] = cres[j];
        }
    }
    __syncthreads();

    // ---- Phase D: stage 3 + ALL global writes (32 cols x 8 groups of 3) ----
    // sc factored out of the 8 non-center taps (verified bit-safe r14-r17).
    {
        const int xD = tid & 31, tyD = tid >> 5;
        const int yd0 = tyD * 3;
        float wdk[9];
        #pragma unroll
        for (int k = 0; k < 9; ++k) wdk[k] = sw[k];
        float  srw[3][3];
        float2 qrw[3][3];
#define HROW_D(rr, slot) { \
        srw[slot][0] = __half2float(s_s[rr][xD]); \
        srw[slot][1] = __half2float(s_s[rr][xD + 1]); \
        srw[slot][2] = __half2float(s_s[rr][xD + 2]); \
        qrw[slot][0] = s_qc[rr + 2][xD + 2]; qrw[slot][1] = s_qc[rr + 2][xD + 3]; qrw[slot][2] = s_qc[rr + 2][xD + 4]; }
        HROW_D(yd0 + 0, 0)
        HROW_D(yd0 + 1, 1)
#define TAP_F(slot, kk, cc2) { \
        float t = wdk[kk] * srw[slot][cc2]; \
        float2 q = qrw[slot][cc2]; \
        dn_p += t; \
        nd_p = fmaf(t, q.x * (q.y + EPSF), nd_p); \
        nc_p = fmaf(t, q.y, nc_p); }
        #pragma unroll
        for (int j = 0; j < 3; ++j) {
            const int sl2 = (j + 2) % 3, s0 = j % 3, s1 = (j + 1) % 3;
            HROW_D(yd0 + j + 2, sl2)
            float sc = srw[s1][1];
            float nd_p = 0.f, nc_p = 0.f, dn_p = 0.f;
            TAP_F(s0, 0, 0) TAP_F(s0, 1, 1) TAP_F(s0, 2, 2)
            TAP_F(s1, 3, 0)                 TAP_F(s1, 5, 2)
            TAP_F(sl2, 6, 0) TAP_F(sl2, 7, 1) TAP_F(sl2, 8, 2)
            const float w4 = wdk[4];
            float2 q4 = qrw[s1][1];
            float d4 = q4.x * (q4.y + EPSF);
            float den = fmaf(sc, dn_p, w4) + EPSF;
            float nd  = fmaf(sc, nd_p, w4 * d4);
            float nc  = fmaf(sc, nc_p, w4 * q4.y);
            float rinv = __builtin_amdgcn_rcpf(den);
            const int iy = yd0 + j;
            int idx = (ty0 + iy) * Ww + (tx0 + xD);
            float2 cv = s_t[iy + 1][xD + 1];   // (accC, accS) for this pixel
            out[(2 * b)     * PLANE + idx] = nd * rinv;   // x_out d-part
            out[(2 * b + 1) * PLANE + idx] = nc * rinv;   // x_out c-part
            out[(8 + b)     * PLANE + idx] = cv.y;        // scs_out
            out[(12 + b)    * PLANE + idx] = cv.x;        // cs_out
        }
    }
}

// 2 vertically-adjacent tiles per block: 1536 blocks = 6/CU, all resident
// from t=0 (zero dispatch tail); weight prep once per block; tile 2's top
// halo rows are tile 1's bottom rows (L2-warm).
__global__ __launch_bounds__(256)
void fused_all(const float* __restrict__ x, const float* __restrict__ scs,
               const float* __restrict__ cs,
               const float* __restrict__ w_sp_d, const float* __restrict__ w_sp_s,
               const float* __restrict__ w_pow_s, const float* __restrict__ w_prop_s,
               float* __restrict__ out) {
    __shared__ Smem sm;
    const int tid = threadIdx.x;

    // ---- parallel weight prep (lanes 0..10 of wave 0; wave-lockstep safe;
    // consumers read sw only after the first __syncthreads inside tile 1) ----
    if (tid < 9) {
        int r = tid / 3, c = tid - r * 3;
        int cc = (c == 2) ? 0 : c;              // mirrored 3rd column
        sm.swraw[tid]     = log1pf(expf(w_sp_d[r * 2 + cc]));
        sm.swraw[9 + tid] = log1pf(expf(w_sp_s[r * 2 + cc]));
    }
    if (tid == 9)  sm.sw[18] = 1.f / (1.f + expf(-w_prop_s[0]));   // wps
    if (tid == 10) sm.sw[19] = log1pf(expf(w_pow_s[0]));           // wpow
    if (tid < 9) {   // same-wave: raw writes complete (lockstep) before reads
        float sum_d = 0.f, sum_s = 0.f;
        #pragma unroll
        for (int k = 0; k < 9; ++k) { sum_d += sm.swraw[k]; sum_s += sm.swraw[9 + k]; }
        sm.sw[tid]     = sm.swraw[tid]     / sum_d;
        sm.sw[9 + tid] = sm.swraw[9 + tid] / sum_s;
    }

    // XCD-bijective swizzle: 1536 = 8 XCDs x 192 (contiguous region each).
    const int orig = blockIdx.x;
    const int swz  = (orig & 7) * 192 + (orig >> 3);
    const int b    = swz / 384;
    const int rem  = swz - b * 384;            // pair index in 16 x 24 grid
    const int tyP  = rem / 24;                 // 0..15
    const int txT  = rem % 24;                 // 0..23
    const int ty1  = 2 * tyP, ty2 = 2 * tyP + 1;
    const bool colEdge = (txT == 0) || (txT == 23);
    const bool e1 = colEdge || (ty1 == 0);
    const bool e2 = colEdge || (ty2 == 31);

    if (e1) tile_body<true >(sm, b, ty1 * TSY, txT * TSX, x, scs, cs, out);
    else    tile_body<false>(sm, b, ty1 * TSY, txT * TSX, x, scs, cs, out);
    __syncthreads();   // tile 1's Phase D reads s_qc/s_s; tile 2's A overwrites
    if (e2) tile_body<true >(sm, b, ty2 * TSY, txT * TSX, x, scs, cs, out);
    else    tile_body<false>(sm, b, ty2 * TSY, txT * TSX, x, scs, cs, out);
}

extern "C" void kernel_launch(void* const* d_in, const int* in_sizes, int n_in,
                              void* d_out, int out_size, void* d_ws, size_t ws_size,
                              hipStream_t stream) {
    const float* x        = (const float*)d_in[0];
    const float* scs      = (const float*)d_in[1];
    const float* cs       = (const float*)d_in[2];
    // d_in[3] = w_channel_d (1,1) -> normalizes to 1, unused
    const float* w_sp_d   = (const float*)d_in[4];
    const float* w_pow_s  = (const float*)d_in[5];
    const float* w_prop_s = (const float*)d_in[6];
    // d_in[7] = w_channel_s (1,1) -> normalizes to 1, unused
    const float* w_sp_s   = (const float*)d_in[8];
    float* out  = (float*)d_out;

    fused_all<<<dim3(1536), 256, 0, stream>>>(x, scs, cs, w_sp_d, w_sp_s,
                                              w_pow_s, w_prop_s, out);
}

// Round 19
// 28.898 us; speedup vs baseline: 1.0565x; 1.0178x over previous
//
#include <hip/hip_runtime.h>
#include <hip/hip_fp16.h>

#define EPSF 1e-20f

constexpr int Hh = 768, Ww = 768, Bb = 4;
constexpr int PLANE = Hh * Ww;
constexpr int TSX = 32, TSY = 24;             // output tile (w x h)
constexpr int R3Y = TSY + 6, R3X = TSX + 6;   // 30 x 38 halo-3 (dq, c)
constexpr int R2Y = TSY + 4, R2X = TSX + 4;   // 28 x 36 halo-2 (tc, ts)
constexpr int R1Y = TSY + 2, R1X = TSX + 2;   // 26 x 34 halo-1 (s)

struct Smem {
    float2 s_qc[R3Y][R3X];   // (.x = dq = d/(c+eps), .y = c)       9120B
    float2 s_t[R2Y][R2X];    // (tc, ts)                            8064B
    float2 cbuf[R1Y][R1X];   // (accC, accS) conv results           7072B
    __half s_s[R1Y][R1X];    // s (half), 0 outside image           1768B
    float  sw[20];           // wd[0..8], ws[9..17], wps, wpow
    float  swraw[18];        // unnormalized softplus values
};  // ~26.2KB -> 6 resident blocks/CU (= the 6/CU we launch; zero cost)

// r18 tile body with C2 deleted: Phase C writes conv results directly to
// cbuf (dedicated LDS, no re-staging barrier); Phase D reads cv from cbuf.
template<bool EDGE>
__device__ __forceinline__
void tile_body(Smem& sm, int b, int ty0, int tx0,
               const float* __restrict__ x, const float* __restrict__ scs,
               const float* __restrict__ cs, float* __restrict__ out) {
    auto& s_qc = sm.s_qc; auto& s_t = sm.s_t; auto& s_s = sm.s_s;
    auto& cbuf = sm.cbuf; auto& sw = sm.sw;

    const int tid = threadIdx.x;
    const float* dcd = x + b * PLANE;
    const float* cd  = x + (Bb + b) * PLANE;

    // ---- Phase A: vectorized load at halo-3 (30 rows x 10 float4 segs) ----
    for (int it = tid; it < R3Y * 10; it += 256) {   // 300 items
        int row = it / 10, seg = it - row * 10;
        int gy = ty0 - 3 + row;
        int gxb = tx0 - 4 + seg * 4;
        float4 vd4, vc4;
        if constexpr (!EDGE) {
            vd4 = *(const float4*)(dcd + gy * Ww + gxb);
            vc4 = *(const float4*)(cd  + gy * Ww + gxb);
        } else {
            vd4 = make_float4(0.f, 0.f, 0.f, 0.f);
            vc4 = vd4;
            if ((unsigned)gy < (unsigned)Hh) {
                bool safe = (seg > 0 && seg < 9) || (seg == 0 ? (tx0 > 0) : (tx0 + TSX < Ww));
                if (safe) {
                    vd4 = *(const float4*)(dcd + gy * Ww + gxb);
                    vc4 = *(const float4*)(cd  + gy * Ww + gxb);
                } else {
                    if ((unsigned)(gxb + 0) < (unsigned)Ww) { vd4.x = dcd[gy*Ww+gxb+0]; vc4.x = cd[gy*Ww+gxb+0]; }
                    if ((unsigned)(gxb + 1) < (unsigned)Ww) { vd4.y = dcd[gy*Ww+gxb+1]; vc4.y = cd[gy*Ww+gxb+1]; }
                    if ((unsigned)(gxb + 2) < (unsigned)Ww) { vd4.z = dcd[gy*Ww+gxb+2]; vc4.z = cd[gy*Ww+gxb+2]; }
                    if ((unsigned)(gxb + 3) < (unsigned)Ww) { vd4.w = dcd[gy*Ww+gxb+3]; vc4.w = cd[gy*Ww+gxb+3]; }
                }
            }
        }
        int lxb = seg * 4 - 1;   // lx of component 0
        if ((unsigned)(lxb + 0) < (unsigned)R3X) s_qc[row][lxb + 0] = make_float2(vd4.x / (vc4.x + EPSF), vc4.x);
        if ((unsigned)(lxb + 1) < (unsigned)R3X) s_qc[row][lxb + 1] = make_float2(vd4.y / (vc4.y + EPSF), vc4.y);
        if ((unsigned)(lxb + 2) < (unsigned)R3X) s_qc[row][lxb + 2] = make_float2(vd4.z / (vc4.z + EPSF), vc4.z);
        if ((unsigned)(lxb + 3) < (unsigned)R3X) s_qc[row][lxb + 3] = make_float2(vd4.w / (vc4.w + EPSF), vc4.w);
    }

    // ---- Prefetch cs/scs for Phase B (36 cols x 7 groups of 4 rows) ----
    const int xB = tid % R2X;          // 0..35
    const int tyB = tid / R2X;         // active < 7 (252 threads)
    const int yb0 = tyB * 4;
    float pcs[4], pscs[4];
    if (tyB < 7) {
        int gx = tx0 - 2 + xB;
        if constexpr (!EDGE) {
            #pragma unroll
            for (int j = 0; j < 4; ++j) {
                int idx = b * PLANE + (ty0 - 2 + yb0 + j) * Ww + gx;
                pcs[j]  = cs[idx];
                pscs[j] = scs[idx];
            }
        } else {
            bool colok = (unsigned)gx < (unsigned)Ww;
            #pragma unroll
            for (int j = 0; j < 4; ++j) {
                int gy = ty0 - 2 + yb0 + j;
                bool ok = colok && (unsigned)gy < (unsigned)Hh;
                int idx = ok ? (b * PLANE + gy * Ww + gx) : 0;
                pcs[j]  = ok ? cs[idx]  : 0.f;
                pscs[j] = ok ? scs[idx] : 0.f;
            }
        }
    }
    __syncthreads();

    const float wps  = sw[18];
    const float wpow = sw[19];
    const float onemw = 1.f - wps;

    // ---- Phase B: stage 1, column sweep. Hierarchical first-wins argmax:
    // row-max over dx (k-minor) then combine over dy (k-major) — exactly
    // reproduces jnp.argmax first-occurrence order.
    if (tyB < 7) {
        float ma[3], md[3], mc[3];    // jmax row-partials (key, dq, c)
        float nv[3], nq[3];           // jmin row-partials (vc, dq+eps)
#define HROW_B(rr, slot) { \
        float2 q0 = s_qc[rr][xB]; float2 q1 = s_qc[rr][xB + 1]; float2 q2 = s_qc[rr][xB + 2]; \
        float a0 = q0.x * q0.y, a1 = q1.x * q1.y, a2 = q2.x * q2.y; \
        float A = a0, D = q0.x, C = q0.y; \
        if (a1 > A) { A = a1; D = q1.x; C = q1.y; } \
        if (a2 > A) { A = a2; D = q2.x; C = q2.y; } \
        ma[slot] = A; md[slot] = D; mc[slot] = C; \
        float V = q0.y, Q = q0.x + EPSF; \
        float e1 = q1.x + EPSF, e2 = q2.x + EPSF; \
        if (q1.y * Q > V * e1) { V = q1.y; Q = e1; } \
        if (q2.y * Q > V * e2) { V = q2.y; Q = e2; } \
        nv[slot] = V; nq[slot] = Q; }
        HROW_B(yb0 + 0, 0)
        HROW_B(yb0 + 1, 1)
        #pragma unroll
        for (int j = 0; j < 4; ++j) {
            const int sl2 = (j + 2) % 3, s0 = j % 3, s1 = (j + 1) % 3;
            HROW_B(yb0 + j + 2, sl2)
            float A = ma[s0], D = md[s0], C = mc[s0];
            if (ma[s1]  > A) { A = ma[s1];  D = md[s1];  C = mc[s1];  }
            if (ma[sl2] > A) { A = ma[sl2]; D = md[sl2]; C = mc[sl2]; }
            float V = nv[s0], Q = nq[s0];
            if (nv[s1]  * Q > V * nq[s1])  { V = nv[s1];  Q = nq[s1];  }
            if (nv[sl2] * Q > V * nq[sl2]) { V = nv[sl2]; Q = nq[sl2]; }
            const int yb = yb0 + j;
            bool in_img;
            if constexpr (!EDGE) in_img = true;
            else {
                const int gy = ty0 - 2 + yb, gx = tx0 - 2 + xB;
                in_img = (unsigned)gy < (unsigned)Hh && (unsigned)gx < (unsigned)Ww;
            }
            float tc = 0.f, ts = 0.f;
            if (in_img) {
                float s_new = __builtin_amdgcn_exp2f(wpow *
                    (__builtin_amdgcn_logf(Q) - __builtin_amdgcn_logf(D + EPSF)));
                float cs_new = C * V;
                tc = pcs[j]  * wps + cs_new * onemw;
                ts = pscs[j] * wps + s_new * cs_new * onemw;
            }
            s_t[yb][xB] = make_float2(tc, ts);
        }
    }
    __syncthreads();

    // ---- Phase C: stage 2 conv, column sweep (34 cols x 7 groups of 4) ----
    // Conv results go DIRECTLY into dedicated cbuf (no re-staging barrier).
    const int xC = tid % R1X;          // 0..33
    const int tyC = tid / R1X;         // active < 7 (238 threads)
    const int yc0 = tyC * 4;
    if (tyC < 7) {
        const float wa0 = sw[9],  wb0 = sw[10];
        const float wa1 = sw[12], wb1 = sw[13];
        const float wa2 = sw[15], wb2 = sw[16];
        float2 u[3], tm[3];
#define HROW_C(rr, slot) { \
        float2 t0 = s_t[rr][xC]; float2 t1 = s_t[rr][xC + 1]; float2 t2 = s_t[rr][xC + 2]; \
        u[slot] = make_float2(t0.x + t2.x, t0.y + t2.y); tm[slot] = t1; }
        HROW_C(yc0 + 0, 0)
        HROW_C(yc0 + 1, 1)
        #pragma unroll
        for (int j = 0; j < 4; ++j) {
            const int yc = yc0 + j;
            if (yc < R1Y) {
                const int sl2 = (j + 2) % 3, s0 = j % 3, s1 = (j + 1) % 3;
                HROW_C(yc + 2, sl2)
                float accC = wa0 * u[s0].x + wb0 * tm[s0].x
                           + wa1 * u[s1].x + wb1 * tm[s1].x
                           + wa2 * u[sl2].x + wb2 * tm[sl2].x;
                float accS = wa0 * u[s0].y + wb0 * tm[s0].y
                           + wa1 * u[s1].y + wb1 * tm[s1].y
                           + wa2 * u[sl2].y + wb2 * tm[sl2].y;
                bool in_img;
                if constexpr (!EDGE) in_img = true;
                else {
                    const int gy = ty0 - 1 + yc, gx = tx0 - 1 + xC;
                    in_img = (unsigned)gy < (unsigned)Hh && (unsigned)gx < (unsigned)Ww;
                }
                s_s[yc][xC] = __float2half(
                    in_img ? (accS * __builtin_amdgcn_rcpf(accC + EPSF)) : 0.f);
                cbuf[yc][xC] = make_float2(accC, accS);
            }
        }
    }
    __syncthreads();   // s_s and cbuf ready

    // ---- Phase D: stage 3 + ALL global writes (32 cols x 8 groups of 3) ----
    // sc factored out of the 8 non-center taps (verified bit-safe r14-r18).
    {
        const int xD = tid & 31, tyD = tid >> 5;
        const int yd0 = tyD * 3;
        float wdk[9];
        #pragma unroll
        for (int k = 0; k < 9; ++k) wdk[k] = sw[k];
        float  srw[3][3];
        float2 qrw[3][3];
#define HROW_D(rr, slot) { \
        srw[slot][0] = __half2float(s_s[rr][xD]); \
        srw[slot][1] = __half2float(s_s[rr][xD + 1]); \
        srw[slot][2] = __half2float(s_s[rr][xD + 2]); \
        qrw[slot][0] = s_qc[rr + 2][xD + 2]; qrw[slot][1] = s_qc[rr + 2][xD + 3]; qrw[slot][2] = s_qc[rr + 2][xD + 4]; }
        HROW_D(yd0 + 0, 0)
        HROW_D(yd0 + 1, 1)
#define TAP_F(slot, kk, cc2) { \
        float t = wdk[kk] * srw[slot][cc2]; \
        float2 q = qrw[slot][cc2]; \
        dn_p += t; \
        nd_p = fmaf(t, q.x * (q.y + EPSF), nd_p); \
        nc_p = fmaf(t, q.y, nc_p); }
        #pragma unroll
        for (int j = 0; j < 3; ++j) {
            const int sl2 = (j + 2) % 3, s0 = j % 3, s1 = (j + 1) % 3;
            HROW_D(yd0 + j + 2, sl2)
            float sc = srw[s1][1];
            float nd_p = 0.f, nc_p = 0.f, dn_p = 0.f;
            TAP_F(s0, 0, 0) TAP_F(s0, 1, 1) TAP_F(s0, 2, 2)
            TAP_F(s1, 3, 0)                 TAP_F(s1, 5, 2)
            TAP_F(sl2, 6, 0) TAP_F(sl2, 7, 1) TAP_F(sl2, 8, 2)
            const float w4 = wdk[4];
            float2 q4 = qrw[s1][1];
            float d4 = q4.x * (q4.y + EPSF);
            float den = fmaf(sc, dn_p, w4) + EPSF;
            float nd  = fmaf(sc, nd_p, w4 * d4);
            float nc  = fmaf(sc, nc_p, w4 * q4.y);
            float rinv = __builtin_amdgcn_rcpf(den);
            const int iy = yd0 + j;
            int idx = (ty0 + iy) * Ww + (tx0 + xD);
            float2 cv = cbuf[iy + 1][xD + 1];   // (accC, accS) for this pixel
            out[(2 * b)     * PLANE + idx] = nd * rinv;   // x_out d-part
            out[(2 * b + 1) * PLANE + idx] = nc * rinv;   // x_out c-part
            out[(8 + b)     * PLANE + idx] = cv.y;        // scs_out
            out[(12 + b)    * PLANE + idx] = cv.x;        // cs_out
        }
    }
}

// 2 vertically-adjacent tiles per block: 1536 blocks = 6/CU, all resident
// from t=0; weight prep once per block; tile 2's top halo is L2-warm.
__global__ __launch_bounds__(256)
void fused_all(const float* __restrict__ x, const float* __restrict__ scs,
               const float* __restrict__ cs,
               const float* __restrict__ w_sp_d, const float* __restrict__ w_sp_s,
               const float* __restrict__ w_pow_s, const float* __restrict__ w_prop_s,
               float* __restrict__ out) {
    __shared__ Smem sm;
    const int tid = threadIdx.x;

    // ---- parallel weight prep (lanes 0..10 of wave 0; wave-lockstep safe;
    // consumers read sw only after the first __syncthreads inside tile 1) ----
    if (tid < 9) {
        int r = tid / 3, c = tid - r * 3;
        int cc = (c == 2) ? 0 : c;              // mirrored 3rd column
        sm.swraw[tid]     = log1pf(expf(w_sp_d[r * 2 + cc]));
        sm.swraw[9 + tid] = log1pf(expf(w_sp_s[r * 2 + cc]));
    }
    if (tid == 9)  sm.sw[18] = 1.f / (1.f + expf(-w_prop_s[0]));   // wps
    if (tid == 10) sm.sw[19] = log1pf(expf(w_pow_s[0]));           // wpow
    if (tid < 9) {   // same-wave: raw writes complete (lockstep) before reads
        float sum_d = 0.f, sum_s = 0.f;
        #pragma unroll
        for (int k = 0; k < 9; ++k) { sum_d += sm.swraw[k]; sum_s += sm.swraw[9 + k]; }
        sm.sw[tid]     = sm.swraw[tid]     / sum_d;
        sm.sw[9 + tid] = sm.swraw[9 + tid] / sum_s;
    }

    // XCD-bijective swizzle: 1536 = 8 XCDs x 192 (contiguous region each).
    const int orig = blockIdx.x;
    const int swz  = (orig & 7) * 192 + (orig >> 3);
    const int b    = swz / 384;
    const int rem  = swz - b * 384;            // pair index in 16 x 24 grid
    const int tyP  = rem / 24;                 // 0..15
    const int txT  = rem % 24;                 // 0..23
    const int ty1  = 2 * tyP, ty2 = 2 * tyP + 1;
    const bool colEdge = (txT == 0) || (txT == 23);
    const bool e1 = colEdge || (ty1 == 0);
    const bool e2 = colEdge || (ty2 == 31);

    if (e1) tile_body<true >(sm, b, ty1 * TSY, txT * TSX, x, scs, cs, out);
    else    tile_body<false>(sm, b, ty1 * TSY, txT * TSX, x, scs, cs, out);
    __syncthreads();   // tile 1's Phase D reads s_qc/s_s; tile 2's A overwrites
    if (e2) tile_body<true >(sm, b, ty2 * TSY, txT * TSX, x, scs, cs, out);
    else    tile_body<false>(sm, b, ty2 * TSY, txT * TSX, x, scs, cs, out);
}

extern "C" void kernel_launch(void* const* d_in, const int* in_sizes, int n_in,
                              void* d_out, int out_size, void* d_ws, size_t ws_size,
                              hipStream_t stream) {
    const float* x        = (const float*)d_in[0];
    const float* scs      = (const float*)d_in[1];
    const float* cs       = (const float*)d_in[2];
    // d_in[3] = w_channel_d (1,1) -> normalizes to 1, unused
    const float* w_sp_d   = (const float*)d_in[4];
    const float* w_pow_s  = (const float*)d_in[5];
    const float* w_prop_s = (const float*)d_in[6];
    // d_in[7] = w_channel_s (1,1) -> normalizes to 1, unused
    const float* w_sp_s   = (const float*)d_in[8];
    float* out  = (float*)d_out;

    fused_all<<<dim3(1536), 256, 0, stream>>>(x, scs, cs, w_sp_d, w_sp_s,
                                              w_pow_s, w_prop_s, out);
}